// Round 1
// baseline (756.566 us; speedup 1.0000x reference)
//
#include <hip/hip_runtime.h>

#define N_PTS 500000
#define FEAT 24
#define HID 168
#define OUT_C 35
#define MT 128          // points per block
#define A1_STR 40       // feat tile row stride (ushorts): 32 pad + 8 -> 2-way banks
#define A2_STR 200      // h tile row stride: 192 pad + 8
#define W2B_STR 40      // staged W2 chunk row stride

// ws layout (bf16 elements):
//   Wt1: 3 x [176][32]   at 0        (3*5632  = 16896)
//   Wt2: 3 x [176][192]  at 16896    (3*33792 = 101376)
//   Wt3: 3 x [48][192]   at 118272   (3*9216  = 27648)   total 145920
#define WT1_OFF 0
#define WT2_OFF 16896
#define WT3_OFF 118272
#define W_TOTAL 145920

typedef short bf16x8 __attribute__((ext_vector_type(8)));
typedef float f32x4 __attribute__((ext_vector_type(4)));

__device__ __forceinline__ unsigned short f2bf(float f) {
    union { float f; unsigned int u; } v; v.f = f;
    unsigned int u = v.u;
    return (unsigned short)((u + 0x7FFFu + ((u >> 16) & 1u)) >> 16);
}

__device__ __forceinline__ f32x4 mfma16(bf16x8 a, bf16x8 b, f32x4 c) {
    return __builtin_amdgcn_mfma_f32_16x16x32_bf16(a, b, c, 0, 0, 0);
}

__global__ __launch_bounds__(256) void prep_weights(
    const float* __restrict__ w1a, const float* __restrict__ w2a, const float* __restrict__ w3a,
    const float* __restrict__ w1b, const float* __restrict__ w2b, const float* __restrict__ w3b,
    const float* __restrict__ w1c, const float* __restrict__ w2c, const float* __restrict__ w3c,
    unsigned short* __restrict__ ws)
{
    int id = blockIdx.x * 256 + threadIdx.x;
    if (id >= W_TOTAL) return;
    const float* w1[3] = {w1a, w1b, w1c};
    const float* w2[3] = {w2a, w2b, w2c};
    const float* w3[3] = {w3a, w3b, w3c};
    float v = 0.f;
    if (id < WT2_OFF) {                       // Wt1[n][k] = w1[k][n], [176][32]
        int s = id / 5632, r = id % 5632, n = r / 32, k = r % 32;
        if (n < HID && k < FEAT) v = w1[s][k * HID + n];
    } else if (id < WT3_OFF) {                // Wt2[n][k] = w2[k][n], [176][192]
        int t = id - WT2_OFF;
        int s = t / 33792, r = t % 33792, n = r / 192, k = r % 192;
        if (n < HID && k < HID) v = w2[s][k * HID + n];
    } else {                                  // Wt3[n][k] = w3[k][n], [48][192]
        int t = id - WT3_OFF;
        int s = t / 9216, r = t % 9216, n = r / 192, k = r % 192;
        if (n < OUT_C && k < HID) v = w3[s][k * OUT_C + n];
    }
    ws[id] = f2bf(v);
}

__global__ __launch_bounds__(256, 2) void tri_mlp(
    const float* __restrict__ xyz,
    const float* __restrict__ xy0, const float* __restrict__ xz0, const float* __restrict__ yz0,
    const float* __restrict__ xy1, const float* __restrict__ xz1, const float* __restrict__ yz1,
    const float* __restrict__ xy2, const float* __restrict__ xz2, const float* __restrict__ yz2,
    const float* __restrict__ b1_0, const float* __restrict__ b2_0, const float* __restrict__ b3_0,
    const float* __restrict__ b1_1, const float* __restrict__ b2_1, const float* __restrict__ b3_1,
    const float* __restrict__ b1_2, const float* __restrict__ b2_2, const float* __restrict__ b3_2,
    const unsigned short* __restrict__ wpack,
    float* __restrict__ out)
{
    __shared__ __align__(16) unsigned short A1[MT * A1_STR];     // 10240 B
    __shared__ __align__(16) unsigned short A2[MT * A2_STR];     // 51200 B
    __shared__ __align__(16) unsigned short W2buf[176 * W2B_STR];// 14080 B

    const int tid  = threadIdx.x;
    const int wave = tid >> 6;
    const int lane = tid & 63;
    const int quad = lane >> 4;
    const int l16  = lane & 15;
    const int p0   = blockIdx.x * MT;

    // zero-init LDS (K-pad columns must be 0; simplest: zero everything once)
    for (int i = tid; i < MT * A1_STR; i += 256) A1[i] = 0;
    for (int i = tid; i < MT * A2_STR; i += 256) A2[i] = 0;

    f32x4 c3[2][3];
    #pragma unroll
    for (int mi = 0; mi < 2; ++mi)
        #pragma unroll
        for (int nt = 0; nt < 3; ++nt)
            c3[mi][nt] = (f32x4){0.f, 0.f, 0.f, 0.f};

    __syncthreads();

    #pragma unroll 1
    for (int s = 0; s < 3; ++s) {
        const float *pxy, *pxz, *pyz, *b1, *b2;
        int S;
        if (s == 0)      { pxy = xy0; pxz = xz0; pyz = yz0; b1 = b1_0; b2 = b2_0; S = 128; }
        else if (s == 1) { pxy = xy1; pxz = xz1; pyz = yz1; b1 = b1_1; b2 = b2_1; S = 256; }
        else             { pxy = xy2; pxz = xz2; pyz = yz2; b1 = b1_2; b2 = b2_2; S = 512; }

        // ---------- sampling: 384 plane-samples -> A1 (feat, bf16) ----------
        for (int smp = tid; smp < 384; smp += 256) {
            int pl = smp >> 7;          // 0=xy 1=xz 2=yz (wave-uniform)
            int p  = smp & 127;
            int gp = p0 + p;
            if (gp >= N_PTS) gp = N_PTS - 1;
            float X = xyz[gp * 3 + 0], Y = xyz[gp * 3 + 1], Z = xyz[gp * 3 + 2];
            float gx, gy;
            const float* plane;
            if (pl == 0)      { gx = Y; gy = X; plane = pxy; }
            else if (pl == 1) { gx = Z; gy = X; plane = pxz; }
            else              { gx = Z; gy = Y; plane = pyz; }
            gx *= 0.5f; gy *= 0.5f;     // nrm = coord/2 for XYZ_MIN=-2, MAX=2
            float ix = (gx + 1.0f) * 0.5f * (float)(S - 1);
            float iy = (gy + 1.0f) * 0.5f * (float)(S - 1);
            float fx = floorf(ix), fy = floorf(iy);
            int x0 = (int)fx, y0 = (int)fy;
            float wx = ix - fx, wy = iy - fy;
            int x0c = min(max(x0, 0), S - 1);
            int x1c = min(x0 + 1, S - 1);
            int y0c = min(max(y0, 0), S - 1);
            int y1c = min(y0 + 1, S - 1);
            int i00 = y0c * S + x0c, i01 = y0c * S + x1c;
            int i10 = y1c * S + x0c, i11 = y1c * S + x1c;
            float w00 = (1.f - wx) * (1.f - wy), w01 = wx * (1.f - wy);
            float w10 = (1.f - wx) * wy,         w11 = wx * wy;
            float vv[8];
            #pragma unroll
            for (int c = 0; c < 8; ++c) {
                const float* pc = plane + c * S * S;
                vv[c] = pc[i00] * w00 + pc[i01] * w01 + pc[i10] * w10 + pc[i11] * w11;
            }
            uint4 pk;
            pk.x = (unsigned int)f2bf(vv[0]) | ((unsigned int)f2bf(vv[1]) << 16);
            pk.y = (unsigned int)f2bf(vv[2]) | ((unsigned int)f2bf(vv[3]) << 16);
            pk.z = (unsigned int)f2bf(vv[4]) | ((unsigned int)f2bf(vv[5]) << 16);
            pk.w = (unsigned int)f2bf(vv[6]) | ((unsigned int)f2bf(vv[7]) << 16);
            *reinterpret_cast<uint4*>(&A1[p * A1_STR + pl * 8]) = pk;
        }
        __syncthreads();   // also orders previous scale's GEMM3 A2-reads before GEMM1 A2-writes

        // ---------- GEMM1: h1 = relu(feat @ W1 + b1) -> A2 ----------
        {
            bf16x8 af[8];
            #pragma unroll
            for (int m = 0; m < 8; ++m)
                af[m] = *(const bf16x8*)&A1[(m * 16 + l16) * A1_STR + quad * 8];
            const unsigned short* w1p = wpack + WT1_OFF + s * 5632;
            #pragma unroll
            for (int ni = 0; ni < 3; ++ni) {
                int nt = wave + ni * 4;
                if (nt < 11) {
                    bf16x8 bfr = *(const bf16x8*)&w1p[(nt * 16 + l16) * 32 + quad * 8];
                    int col = nt * 16 + l16;
                    float bias = (col < HID) ? b1[col] : 0.f;
                    #pragma unroll
                    for (int m = 0; m < 8; ++m) {
                        f32x4 c = (f32x4){0.f, 0.f, 0.f, 0.f};
                        c = mfma16(af[m], bfr, c);
                        #pragma unroll
                        for (int r = 0; r < 4; ++r) {
                            float v = fmaxf(c[r] + bias, 0.f);
                            A2[(m * 16 + quad * 4 + r) * A2_STR + col] = f2bf(v);
                        }
                    }
                }
            }
        }

        // ---------- GEMM2: h2 = relu(h1 @ W2 + b2), W2 streamed via LDS ----------
        f32x4 c2[3][8];
        #pragma unroll
        for (int ni = 0; ni < 3; ++ni)
            #pragma unroll
            for (int m = 0; m < 8; ++m)
                c2[ni][m] = (f32x4){0.f, 0.f, 0.f, 0.f};
        {
            const unsigned short* w2p = wpack + WT2_OFF + s * 33792;
            #pragma unroll 1
            for (int kk = 0; kk < 6; ++kk) {
                // stage Wt2[:, kk*32 : +32] -> W2buf[176][40]
                for (int i = tid; i < 176 * 4; i += 256) {
                    int n = i >> 2, kq = i & 3;
                    *reinterpret_cast<uint4*>(&W2buf[n * W2B_STR + kq * 8]) =
                        *reinterpret_cast<const uint4*>(&w2p[n * 192 + kk * 32 + kq * 8]);
                }
                __syncthreads();  // stage done + (kk==0) h1 writes done
                bf16x8 af[8];
                #pragma unroll
                for (int m = 0; m < 8; ++m)
                    af[m] = *(const bf16x8*)&A2[(m * 16 + l16) * A2_STR + kk * 32 + quad * 8];
                #pragma unroll
                for (int ni = 0; ni < 3; ++ni) {
                    int nt = wave + ni * 4;
                    if (nt < 11) {
                        bf16x8 bfr = *(const bf16x8*)&W2buf[(nt * 16 + l16) * W2B_STR + quad * 8];
                        #pragma unroll
                        for (int m = 0; m < 8; ++m)
                            c2[ni][m] = mfma16(af[m], bfr, c2[ni][m]);
                    }
                }
                __syncthreads();  // all reads done before next stage overwrites W2buf
            }
            // write h2 into A2 (all A2 h1-reads completed at last barrier)
            #pragma unroll
            for (int ni = 0; ni < 3; ++ni) {
                int nt = wave + ni * 4;
                if (nt < 11) {
                    int col = nt * 16 + l16;
                    float bias = (col < HID) ? b2[col] : 0.f;
                    #pragma unroll
                    for (int m = 0; m < 8; ++m) {
                        #pragma unroll
                        for (int r = 0; r < 4; ++r) {
                            float v = fmaxf(c2[ni][m][r] + bias, 0.f);
                            A2[(m * 16 + quad * 4 + r) * A2_STR + col] = f2bf(v);
                        }
                    }
                }
            }
        }
        __syncthreads();

        // ---------- GEMM3: tmp += h2 @ W3 (bias added in epilogue) ----------
        {
            const unsigned short* w3p = wpack + WT3_OFF + s * 9216;
            int m0g = wave * 2;
            #pragma unroll
            for (int kk = 0; kk < 6; ++kk) {
                bf16x8 a0 = *(const bf16x8*)&A2[((m0g    ) * 16 + l16) * A2_STR + kk * 32 + quad * 8];
                bf16x8 a1 = *(const bf16x8*)&A2[((m0g + 1) * 16 + l16) * A2_STR + kk * 32 + quad * 8];
                #pragma unroll
                for (int nt = 0; nt < 3; ++nt) {
                    bf16x8 bfr = *(const bf16x8*)&w3p[(nt * 16 + l16) * 192 + kk * 32 + quad * 8];
                    c3[0][nt] = mfma16(a0, bfr, c3[0][nt]);
                    c3[1][nt] = mfma16(a1, bfr, c3[1][nt]);
                }
            }
        }
        // no barrier needed here: next iteration's sampling touches only A1,
        // and the post-sampling barrier orders GEMM3 reads vs GEMM1 writes.
    }

    // ---------- epilogue ----------
    {
        int m0g = wave * 2;
        #pragma unroll
        for (int mi = 0; mi < 2; ++mi) {
            #pragma unroll
            for (int nt = 0; nt < 3; ++nt) {
                int col = nt * 16 + l16;
                if (col < OUT_C) {
                    float bsum = b3_0[col] + b3_1[col] + b3_2[col];
                    #pragma unroll
                    for (int r = 0; r < 4; ++r) {
                        int row = p0 + (m0g + mi) * 16 + quad * 4 + r;
                        if (row < N_PTS) {
                            float v = c3[mi][nt][r] + bsum;
                            if (col >= 31 && col < 34)      v = 1.0f / (1.0f + expf(-v));
                            else if (col == 34)             v *= 10.0f;
                            out[row * OUT_C + col] = v;
                        }
                    }
                }
            }
        }
    }
}

extern "C" void kernel_launch(void* const* d_in, const int* in_sizes, int n_in,
                              void* d_out, int out_size, void* d_ws, size_t ws_size,
                              hipStream_t stream) {
    (void)in_sizes; (void)n_in; (void)out_size; (void)ws_size;
    const float* xyz  = (const float*)d_in[0];
    const float* xy0  = (const float*)d_in[1];
    const float* xz0  = (const float*)d_in[2];
    const float* yz0  = (const float*)d_in[3];
    const float* w1_0 = (const float*)d_in[4];
    const float* b1_0 = (const float*)d_in[5];
    const float* w2_0 = (const float*)d_in[6];
    const float* b2_0 = (const float*)d_in[7];
    const float* w3_0 = (const float*)d_in[8];
    const float* b3_0 = (const float*)d_in[9];
    const float* xy1  = (const float*)d_in[10];
    const float* xz1  = (const float*)d_in[11];
    const float* yz1  = (const float*)d_in[12];
    const float* w1_1 = (const float*)d_in[13];
    const float* b1_1 = (const float*)d_in[14];
    const float* w2_1 = (const float*)d_in[15];
    const float* b2_1 = (const float*)d_in[16];
    const float* w3_1 = (const float*)d_in[17];
    const float* b3_1 = (const float*)d_in[18];
    const float* xy2  = (const float*)d_in[19];
    const float* xz2  = (const float*)d_in[20];
    const float* yz2  = (const float*)d_in[21];
    const float* w1_2 = (const float*)d_in[22];
    const float* b1_2 = (const float*)d_in[23];
    const float* w2_2 = (const float*)d_in[24];
    const float* b2_2 = (const float*)d_in[25];
    const float* w3_2 = (const float*)d_in[26];
    const float* b3_2 = (const float*)d_in[27];

    unsigned short* ws = (unsigned short*)d_ws;
    float* out = (float*)d_out;

    prep_weights<<<(W_TOTAL + 255) / 256, 256, 0, stream>>>(
        w1_0, w2_0, w3_0, w1_1, w2_1, w3_1, w1_2, w2_2, w3_2, ws);

    tri_mlp<<<(N_PTS + MT - 1) / MT, 256, 0, stream>>>(
        xyz, xy0, xz0, yz0, xy1, xz1, yz1, xy2, xz2, yz2,
        b1_0, b2_0, b3_0, b1_1, b2_1, b3_1, b1_2, b2_2, b3_2,
        ws, out);
}